// Round 13
// baseline (165.850 us; speedup 1.0000x reference)
//
#include <hip/hip_runtime.h>

#define B_  2
#define T_  2048
#define C_  1024
#define H_  16
#define D_  64
#define M_  (B_*T_)   // 4096
#define N1_ (3*C_)    // 3072

typedef short bf16x8 __attribute__((ext_vector_type(8)));
typedef short bf16x4 __attribute__((ext_vector_type(4)));
typedef float f32x4 __attribute__((ext_vector_type(4)));
typedef unsigned short u16;
typedef u16 u16x8 __attribute__((ext_vector_type(8)));

#define QSCALE 0.18033688011112042f   // (1/8) * log2(e)
#define C8     11.541560327111707f    // 8 * log2(e)

__device__ __forceinline__ u16 f2bf(float f) {
  unsigned u = __float_as_uint(f);
  u += 0x7FFFu + ((u >> 16) & 1u);
  return (u16)(u >> 16);
}

#if __has_builtin(__builtin_amdgcn_mfma_f32_16x16x16bf16_1k)
__device__ __forceinline__ f32x4 mfma16(bf16x4 a, bf16x4 b, f32x4 c) {
  return __builtin_amdgcn_mfma_f32_16x16x16bf16_1k(a, b, c, 0, 0, 0);
}
#define V_STRIDE4 1   // B loads at kv = base + kg*4 + j
#else
// fallback: zero-padded K=32 (logical k -> kv = (k>>3)*4 + (k&3); A zero for k&7>=4)
__device__ __forceinline__ f32x4 mfma16(bf16x4 a, bf16x4 b, f32x4 c) {
  bf16x8 a8 = {a[0], a[1], a[2], a[3], 0, 0, 0, 0};
  bf16x8 b8 = {b[0], b[1], b[2], b[3], 0, 0, 0, 0};
  return __builtin_amdgcn_mfma_f32_16x16x32_bf16(a8, b8, c, 0, 0, 0);
}
#define V_STRIDE4 1
#endif

__device__ __forceinline__ void gload16(const void* g, void* l) {
  __builtin_amdgcn_global_load_lds((__attribute__((address_space(1))) void*)g,
                                   (__attribute__((address_space(3))) void*)l,
                                   16, 0, 0);
}

// ---------------- fp32 -> bf16 conversion ----------------
__global__ __launch_bounds__(256) void cvt_bf16(const float* __restrict__ in,
                                                u16* __restrict__ out, int n) {
  int i = (blockIdx.x * 256 + threadIdx.x) * 8;
  if (i >= n) return;
  float4 a = *(const float4*)(in + i);
  float4 b = *(const float4*)(in + i + 4);
  u16x8 o;
  o[0] = f2bf(a.x); o[1] = f2bf(a.y); o[2] = f2bf(a.z); o[3] = f2bf(a.w);
  o[4] = f2bf(b.x); o[5] = f2bf(b.y); o[6] = f2bf(b.z); o[7] = f2bf(b.w);
  *(u16x8*)(out + i) = o;
}

// ---------------- shared GEMM mainloop: C += A[M,K] * W[N,K]^T ----------------
__device__ __forceinline__ void gemm_core(const u16* __restrict__ A,
                                          const u16* __restrict__ W,
                                          u16* As, u16* Bs,
                                          f32x4 (&acc)[4][4],
                                          int m0, int n0, int K) {
  int tid = threadIdx.x;
  int lane = tid & 63, wid = tid >> 6;
  int wr = wid >> 1, wc = wid & 1;

  int arow = wid * 16 + (lane >> 2);
  int ag = lane & 3;
  int sg = ag ^ ((arow >> 1) & 3);
  const u16* aSrc0 = A + (m0 + arow) * K + sg * 8;
  const u16* aSrc1 = aSrc0 + 64 * K;
  const u16* bSrc0 = W + (n0 + arow) * K + sg * 8;
  const u16* bSrc1 = bSrc0 + 64 * K;
  u16* aDst0 = As + (wid * 16) * 32;
  u16* aDst1 = As + (64 + wid * 16) * 32;
  u16* bDst0 = Bs + (wid * 16) * 32;
  u16* bDst1 = Bs + (64 + wid * 16) * 32;

  int rg = lane >> 4;
  int aoff[4], boff[4];
#pragma unroll
  for (int m = 0; m < 4; ++m) {
    int row = wr * 64 + m * 16 + (lane & 15);
    aoff[m] = row * 32 + (rg ^ ((row >> 1) & 3)) * 8;
    row = wc * 64 + m * 16 + (lane & 15);
    boff[m] = row * 32 + (rg ^ ((row >> 1) & 3)) * 8;
  }

  for (int kt = 0; kt < K / 32; ++kt) {
    int k0 = kt * 32;
    __syncthreads();
    gload16(aSrc0 + k0, aDst0);
    gload16(aSrc1 + k0, aDst1);
    gload16(bSrc0 + k0, bDst0);
    gload16(bSrc1 + k0, bDst1);
    __syncthreads();

    bf16x8 af[4], bfr[4];
#pragma unroll
    for (int m = 0; m < 4; ++m) af[m] = *(const bf16x8*)(As + aoff[m]);
#pragma unroll
    for (int n = 0; n < 4; ++n) bfr[n] = *(const bf16x8*)(Bs + boff[n]);
#pragma unroll
    for (int m = 0; m < 4; ++m)
#pragma unroll
      for (int n = 0; n < 4; ++n)
        acc[m][n] = __builtin_amdgcn_mfma_f32_16x16x32_bf16(af[m], bfr[n], acc[m][n], 0, 0, 0);
  }
}

// ---------------- GEMM1: qkv = x @ W_attn^T + b; Q pre-scaled by log2e/8 ----------------
__global__ __launch_bounds__(256) void gemm_qkv(const u16* __restrict__ A,
                                                const u16* __restrict__ W,
                                                const float* __restrict__ bias,
                                                u16* __restrict__ Qb,
                                                u16* __restrict__ Kb,
                                                u16* __restrict__ Vt) {
  __shared__ __align__(16) u16 As[128 * 32];
  __shared__ __align__(16) u16 Bs[128 * 32];
  f32x4 acc[4][4] = {};
  int m0 = blockIdx.x * 128, n0 = blockIdx.y * 128;
  gemm_core(A, W, As, Bs, acc, m0, n0, C_);

  int lane = threadIdx.x & 63, wid = threadIdx.x >> 6;
  int wr = wid >> 1, wc = wid & 1;
  int rg = lane >> 4, cl = lane & 15;
#pragma unroll
  for (int n = 0; n < 4; ++n) {
    int gn = n0 + wc * 64 + n * 16 + cl;
    float bv = bias[gn];
    int seg = gn >> 10, cc = gn & 1023;
    int h = cc >> 6, d = cc & 63;
    float sc = (seg == 0) ? QSCALE : 1.0f;
#pragma unroll
    for (int m = 0; m < 4; ++m) {
#pragma unroll
      for (int r = 0; r < 4; ++r) {
        int gm = m0 + wr * 64 + m * 16 + rg * 4 + r;
        int b = gm >> 11, t = gm & 2047;
        u16 val = f2bf((acc[m][n][r] + bv) * sc);
        int bh = b * 16 + h;
        if (seg == 0)      Qb[(bh * 2048 + t) * 64 + d] = val;
        else if (seg == 1) Kb[(bh * 2048 + t) * 64 + d] = val;
        else               Vt[(bh * 64 + d) * 2048 + t] = val;
      }
    }
  }
}

// ---------------- GEMM2: out = y @ W_proj^T + b (fp32 out) ----------------
__global__ __launch_bounds__(256) void gemm_proj(const u16* __restrict__ A,
                                                 const u16* __restrict__ W,
                                                 const float* __restrict__ bias,
                                                 float* __restrict__ out) {
  __shared__ __align__(16) u16 As[128 * 32];
  __shared__ __align__(16) u16 Bs[128 * 32];
  f32x4 acc[4][4] = {};
  int m0 = blockIdx.x * 128, n0 = blockIdx.y * 128;
  gemm_core(A, W, As, Bs, acc, m0, n0, C_);

  int lane = threadIdx.x & 63, wid = threadIdx.x >> 6;
  int wr = wid >> 1, wc = wid & 1;
  int rg = lane >> 4, cl = lane & 15;
#pragma unroll
  for (int n = 0; n < 4; ++n) {
    int gn = n0 + wc * 64 + n * 16 + cl;
    float bv = bias[gn];
#pragma unroll
    for (int m = 0; m < 4; ++m) {
#pragma unroll
      for (int r = 0; r < 4; ++r) {
        int gm = m0 + wr * 64 + m * 16 + rg * 4 + r;
        out[gm * 1024 + gn] = acc[m][n][r] + bv;
      }
    }
  }
}

// ---------------- flash attention v13: kv-split + register-direct PV ----------------
// v12 structure (kv-split 2-wave blocks, K ping-pong, bh=bid&31 locality),
// but PV uses 16x16x16 MFMA whose A-layout (k = kg*4+j) matches S^T's lane
// layout exactly -> P feeds PV straight from registers. P LDS tile, its
// swizzle math, and both lgkm round-trips are deleted. V loads become 8x b64
// at matching kv positions (same bytes).
__global__ __launch_bounds__(128, 2) void attn_fwd(const u16* __restrict__ Qb,
                                                   const u16* __restrict__ Kb,
                                                   const u16* __restrict__ Vt,
                                                   u16* __restrict__ Yb) {
  __shared__ __align__(16) f32x4 Co[8][64];      // wave1 o partials
  __shared__ float Cl[2][64];                    // wave1 l partials
  int tid = threadIdx.x, lane = tid & 63, wid = tid >> 6;
  int cl = lane & 15, kg = lane >> 4;
  int bid = blockIdx.x;
  int bh = bid & 31;                   // CU-local head
  int qwi = 63 - (bid >> 5);           // heavy-first
  int qw0 = qwi * 32;
  int jmax = qwi >> 1;
  int fc0 = wid * 2;                   // this wave's fc pair
  const u16* Qp = Qb + (size_t)bh * (2048 * 64);
  const u16* Kp = Kb + (size_t)bh * (2048 * 64);
  const u16* Vp = Vt + (size_t)bh * (64 * 2048);

  int kbase = cl * 64 + kg * 8 + fc0 * 1024;    // + fcl*1024 + j*4096 (+32 dk)
  int vbase = cl * 2048 + wid * 32 + kg * 4;    // + dc*32768 + fcl*16 + j*64

  // Q fragments (B-operand): q = qw0 + fr*16 + cl, d-slice dk*32 + kg*8
  bf16x8 qf[2][2];
#pragma unroll
  for (int fr = 0; fr < 2; ++fr)
#pragma unroll
    for (int dk = 0; dk < 2; ++dk)
      qf[fr][dk] = *(const bf16x8*)(Qp + (qw0 + fr * 16 + cl) * 64 + dk * 32 + kg * 8);

  f32x4 o[2][4] = {};
  float lsum[2] = {0.f, 0.f};
  const f32x4 CINIT = {-C8, -C8, -C8, -C8};

  auto LOADK = [&](bf16x8 (&kf)[2][2], int j) {
    const u16* Kj = Kp + j * 4096 + kbase;
#pragma unroll
    for (int fcl = 0; fcl < 2; ++fcl) {
      kf[fcl][0] = *(const bf16x8*)(Kj + fcl * 1024);
      kf[fcl][1] = *(const bf16x8*)(Kj + fcl * 1024 + 32);
    }
  };

  auto CORE = [&](bf16x8 (&kf)[2][2], int j, bool edge) {
    // V frags (B-operand of 16x16x16): d = dc*16+cl, kv = fcl*16 + kg*4 + r
    bf16x4 vf[2][4];
    const u16* Vj = Vp + j * 64 + vbase;
#pragma unroll
    for (int fcl = 0; fcl < 2; ++fcl)
#pragma unroll
      for (int dc = 0; dc < 4; ++dc)
        vf[fcl][dc] = *(const bf16x4*)(Vj + dc * 32768 + fcl * 16);

    // S^T = K Q^T - C8 : lane holds q = fr*16+cl, kv = (fc0+fcl)*16 + kg*4 + r
    f32x4 s[2][2];
#pragma unroll
    for (int fcl = 0; fcl < 2; ++fcl)
#pragma unroll
      for (int fr = 0; fr < 2; ++fr) {
        f32x4 z = CINIT;
        z = __builtin_amdgcn_mfma_f32_16x16x32_bf16(kf[fcl][0], qf[fr][0], z, 0, 0, 0);
        z = __builtin_amdgcn_mfma_f32_16x16x32_bf16(kf[fcl][1], qf[fr][1], z, 0, 0, 0);
        s[fr][fcl] = z;
      }
    if (edge) {
#pragma unroll
      for (int fr = 0; fr < 2; ++fr) {
        int qg = qw0 + fr * 16 + cl;
#pragma unroll
        for (int fcl = 0; fcl < 2; ++fcl)
#pragma unroll
          for (int r = 0; r < 4; ++r)
            if (j * 64 + (fc0 + fcl) * 16 + kg * 4 + r > qg) s[fr][fcl][r] = -1e30f;
      }
    }

    // P = exp2(S) -> bf16x4 in-register; PV direct (A-layout k=kg*4+j matches)
#pragma unroll
    for (int fr = 0; fr < 2; ++fr)
#pragma unroll
      for (int fcl = 0; fcl < 2; ++fcl) {
        bf16x4 pw;
#pragma unroll
        for (int r = 0; r < 4; ++r) {
          float p = exp2f(s[fr][fcl][r]);
          lsum[fr] += p;
          pw[r] = (short)f2bf(p);
        }
#pragma unroll
        for (int dc = 0; dc < 4; ++dc)
          o[fr][dc] = mfma16(pw, vf[fcl][dc], o[fr][dc]);
      }
  };

  bool edgeMine = (fc0 <= ((qwi & 1) ? 3 : 1));  // wave1 idle on even-qwi edge

  bf16x8 kA[2][2], kB[2][2];
  LOADK(kA, 0);
  if (jmax == 0) {
    if (edgeMine) CORE(kA, 0, true);
  } else {
    LOADK(kB, 1);
    int j = 0;
    while (j + 1 < jmax) {
      CORE(kA, j, false);
      LOADK(kA, j + 2);
      CORE(kB, j + 1, false);
      LOADK(kB, (j + 3 <= jmax) ? j + 3 : jmax);
      j += 2;
    }
    if (j < jmax) { CORE(kA, j, false); if (edgeMine) CORE(kB, jmax, true); }
    else          { if (edgeMine) CORE(kA, jmax, true); }
  }

  // combine: wave1 publishes partials; wave0 reduces, normalizes, stores
  if (wid == 1) {
#pragma unroll
    for (int fr = 0; fr < 2; ++fr) {
      Cl[fr][lane] = lsum[fr];
#pragma unroll
      for (int dc = 0; dc < 4; ++dc) Co[fr * 4 + dc][lane] = o[fr][dc];
    }
  }
  __syncthreads();
  if (wid == 0) {
    int b = bh >> 4, h = bh & 15;
#pragma unroll
    for (int fr = 0; fr < 2; ++fr) {
      float l = lsum[fr] + Cl[fr][lane];
#pragma unroll
      for (int dc = 0; dc < 4; ++dc) o[fr][dc] += Co[fr * 4 + dc][lane];
      l += __shfl_xor(l, 16);
      l += __shfl_xor(l, 32);
      float linv = 1.f / l;
      float li[4];
#pragma unroll
      for (int r = 0; r < 4; ++r) li[r] = __shfl(linv, kg * 4 + r);
#pragma unroll
      for (int dc = 0; dc < 4; ++dc)
#pragma unroll
        for (int r = 0; r < 4; ++r) {
          int t = qw0 + fr * 16 + kg * 4 + r;
          int d = dc * 16 + cl;
          Yb[((size_t)(b * 2048 + t)) * 1024 + h * 64 + d] = f2bf(o[fr][dc][r] * li[r]);
        }
    }
  }
}

extern "C" void kernel_launch(void* const* d_in, const int* in_sizes, int n_in,
                              void* d_out, int out_size, void* d_ws, size_t ws_size,
                              hipStream_t stream) {
  const float* x  = (const float*)d_in[0];
  const float* Wa = (const float*)d_in[1];
  const float* ba = (const float*)d_in[2];
  const float* Wp = (const float*)d_in[3];
  const float* bp = (const float*)d_in[4];
  float* out = (float*)d_out;

  u16* xb  = (u16*)d_ws;
  u16* Wab = xb  + (size_t)M_ * C_;
  u16* Wpb = Wab + (size_t)N1_ * C_;
  u16* Qb  = Wpb + (size_t)C_ * C_;
  u16* Kb  = Qb  + (size_t)M_ * C_;
  u16* Vt  = Kb  + (size_t)M_ * C_;
  u16* Yb  = Vt  + (size_t)M_ * C_;

  cvt_bf16<<<(M_ * C_) / 2048, 256, 0, stream>>>(x, xb, M_ * C_);
  cvt_bf16<<<(N1_ * C_) / 2048, 256, 0, stream>>>(Wa, Wab, N1_ * C_);
  cvt_bf16<<<(C_ * C_) / 2048, 256, 0, stream>>>(Wp, Wpb, C_ * C_);
  gemm_qkv<<<dim3(M_ / 128, N1_ / 128), 256, 0, stream>>>(xb, Wab, ba, Qb, Kb, Vt);
  attn_fwd<<<2048, 128, 0, stream>>>(Qb, Kb, Vt, Yb);
  gemm_proj<<<dim3(M_ / 128, C_ / 128), 256, 0, stream>>>(Yb, Wpb, bp, out);
}